// Round 1
// baseline (92.140 us; speedup 1.0000x reference)
//
#include <hip/hip_runtime.h>

// LocalConvolutionMixMerge: per-pixel local convolution with 3x3 and 5x5
// kernels whose weights are shared across 8 channel groups (c % 32).
//
// x:      [N=2, C=256, H=64, W=64] fp32
// weight: [N=2, 1088, H, W] fp32  (1088 = 32*9 + 32*25)
//   w1[n, wc, t, h, w] = weight[n, wc*9  + t,        h, w]  (t in 0..8,  3x3, pad 1)
//   w2[n, wc, t, h, w] = weight[n, 288 + wc*25 + t,  h, w]  (t in 0..24, 5x5, pad 2)
// out:    [N, 2, 1, 256, H, W] fp32
//   out[n,0,0,c,h,w] = sum_t x[n,c,h+t/3-1,w+t%3-1] * w1[n,c%32,t,h,w]
//   out[n,1,0,c,h,w] = sum_t x[n,c,h+t/5-2,w+t%5-2] * w2[n,c%32,t,h,w]
//
// One thread per (n, wc, h, w), looping over the 8 channel groups so the 34
// per-pixel weights are loaded once and reused 8x. Lanes map to consecutive
// w -> all global accesses coalesced.

#define HW_ (64 * 64)

__global__ __launch_bounds__(256) void lconv_mix_kernel(
    const float* __restrict__ x, const float* __restrict__ wgt,
    float* __restrict__ out) {
  int idx = blockIdx.x * blockDim.x + threadIdx.x;  // N*32*64*64 = 262144
  int w  = idx & 63;
  int h  = (idx >> 6) & 63;
  int wc = (idx >> 12) & 31;
  int n  = idx >> 17;

  const float* wbase = wgt + (size_t)n * 1088 * HW_ + h * 64 + w;

  float w1[9];
  float w2[25];
#pragma unroll
  for (int t = 0; t < 9; ++t) w1[t] = wbase[(size_t)(wc * 9 + t) * HW_];
#pragma unroll
  for (int t = 0; t < 25; ++t) w2[t] = wbase[(size_t)(288 + wc * 25 + t) * HW_];

  const float* xn = x + (size_t)n * 256 * HW_;
  float* o1 = out + ((size_t)(n * 2 + 0) * 256) * HW_ + h * 64 + w;
  float* o2 = out + ((size_t)(n * 2 + 1) * 256) * HW_ + h * 64 + w;

#pragma unroll
  for (int g = 0; g < 8; ++g) {
    int cc = g * 32 + wc;
    const float* xc = xn + (size_t)cc * HW_;

    // Load 5x5 neighborhood (covers the 3x3 inner window too), zero-padded.
    float v[5][5];
#pragma unroll
    for (int i = 0; i < 5; ++i) {
      int hh = h + i - 2;
      bool hok = (hh >= 0) & (hh < 64);
#pragma unroll
      for (int j = 0; j < 5; ++j) {
        int ww = w + j - 2;
        bool ok = hok & (ww >= 0) & (ww < 64);
        v[i][j] = ok ? xc[hh * 64 + ww] : 0.0f;
      }
    }

    float a1 = 0.0f;
#pragma unroll
    for (int i = 0; i < 3; ++i)
#pragma unroll
      for (int j = 0; j < 3; ++j)
        a1 = fmaf(v[i + 1][j + 1], w1[i * 3 + j], a1);

    float a2 = 0.0f;
#pragma unroll
    for (int i = 0; i < 5; ++i)
#pragma unroll
      for (int j = 0; j < 5; ++j)
        a2 = fmaf(v[i][j], w2[i * 5 + j], a2);

    o1[(size_t)cc * HW_] = a1;
    o2[(size_t)cc * HW_] = a2;
  }
}

extern "C" void kernel_launch(void* const* d_in, const int* in_sizes, int n_in,
                              void* d_out, int out_size, void* d_ws,
                              size_t ws_size, hipStream_t stream) {
  const float* x = (const float*)d_in[0];
  const float* wgt = (const float*)d_in[1];
  float* out = (float*)d_out;

  int total = 2 * 32 * 64 * 64;  // N * WC * H * W
  dim3 block(256);
  dim3 grid(total / 256);
  lconv_mix_kernel<<<grid, block, 0, stream>>>(x, wgt, out);
}